// Round 1
// baseline (79.610 us; speedup 1.0000x reference)
//
#include <hip/hip_runtime.h>

#define NP 64
#define NV 2562
#define KK 192
#define LDP 200          // LDS row pitch in shorts: 192 + 8 pad = 400B (16B-aligned rows)
#define GXN 81           // n-blocks: 32 v each (81*32 = 2592 >= 2562)
#define GYM 8            // bs-blocks: 32 bs each (8*32 = 256)

typedef short bf16x8 __attribute__((ext_vector_type(8)));
typedef float f32x4  __attribute__((ext_vector_type(4)));
typedef unsigned int u32x4 __attribute__((ext_vector_type(4)));

// RNE float->bf16
static __device__ __forceinline__ unsigned short f2bf(float x) {
    unsigned u = __float_as_uint(x);
    return (unsigned short)((u + 0x7fffu + ((u >> 16) & 1u)) >> 16);
}
static __device__ __forceinline__ unsigned pack2(float lo, float hi) {
    return (unsigned)f2bf(lo) | ((unsigned)f2bf(hi) << 16);
}

// One fused kernel: no workspace, one launch.
// Block = (bx, by): bx picks 32 vertices, by picks 32 bs.
// Phase 1: all 256 threads build B-tile (32v x 192 bf16), A-tile (128 x 192 bf16,
//          row bs*4+3 zero-padded), and fp32 aux[32][12] in LDS.
// Phase 2: the verified 2x2-tile 16x16x32 bf16 MFMA loop + fp32 epilogue.
__global__ __launch_bounds__(256) void fused_kernel(
    const float* __restrict__ scales,      // [256]
    const float* __restrict__ transforms,  // [256][64][6]
    const float* __restrict__ weights,     // [256][64]
    const float* __restrict__ offsets,     // [64][2562][3]
    const float* __restrict__ bverts,      // [2562][3]
    float* __restrict__ out)               // [256][2562][3]
{
    __shared__ __align__(16) unsigned short Ash[128 * LDP]; // 51200 B
    __shared__ __align__(16) unsigned short Bsh[32 * LDP];  // 12800 B
    __shared__ __align__(16) float auxsh[32 * 12];          // 1536 B -> total 65536 B

    const int t  = threadIdx.x;
    const int bx = blockIdx.x;
    const int by = blockIdx.y;

    // ---------------- phase 1a: B tile -> LDS bf16 ----------------
    {
        const int vloc = t >> 3;               // 0..31
        const int pc   = t & 7;                // 0..7
        const int v    = bx * 32 + vloc;
        const bool live = (v < NV);
        float f[24];
#pragma unroll
        for (int pi = 0; pi < 8; ++pi) {
            const int p = pc * 8 + pi;
            float o0 = 0.f, o1 = 0.f, o2 = 0.f;
            if (live) {
                const float* o = offsets + ((size_t)p * NV + v) * 3;
                o0 = o[0]; o1 = o[1]; o2 = o[2];
            }
            f[pi * 3 + 0] = o0; f[pi * 3 + 1] = o1; f[pi * 3 + 2] = o2;
        }
        unsigned short* d = Bsh + vloc * LDP + pc * 24;    // pc*48B, 16B aligned
        u32x4 w0 = { pack2(f[0],f[1]),   pack2(f[2],f[3]),   pack2(f[4],f[5]),   pack2(f[6],f[7]) };
        u32x4 w1 = { pack2(f[8],f[9]),   pack2(f[10],f[11]), pack2(f[12],f[13]), pack2(f[14],f[15]) };
        u32x4 w2 = { pack2(f[16],f[17]), pack2(f[18],f[19]), pack2(f[20],f[21]), pack2(f[22],f[23]) };
        *reinterpret_cast<u32x4*>(d)      = w0;
        *reinterpret_cast<u32x4*>(d + 8)  = w1;
        *reinterpret_cast<u32x4*>(d + 16) = w2;
    }

    // ---------------- phase 1b: A tile + aux ----------------
    {
        const int bsl = t >> 3;                // 0..31 local bs
        const int pg  = t & 7;                 // p-group: p = pg*8..pg*8+7
        const int bs  = by * 32 + bsl;
        const float sc = scales[bs];

        float racc[12];
#pragma unroll
        for (int k = 0; k < 12; ++k) racc[k] = 0.f;
        unsigned aw[36];                       // 3 rows x 12 packed-bf16 words
#pragma unroll
        for (int k = 0; k < 36; ++k) aw[k] = 0u;

#pragma unroll
        for (int pi = 0; pi < 8; ++pi) {
            const int p = pg * 8 + pi;
            const float* tr = transforms + ((size_t)bs * NP + p) * 6;
            const float tx = tr[0], ty = tr[1], tz = tr[2];
            const float ax = tr[3], ay = tr[4], az = tr[5];
            const float wgt = weights[bs * NP + p];
            const float ws  = wgt * sc;

            float sx, cx, sy, cy, sz, cz;
            __sincosf(ax, &sx, &cx);
            __sincosf(ay, &sy, &cy);
            __sincosf(az, &sz, &cz);

            float r[12];
            r[0] = (cy * cz) * ws;
            r[1] = (-cy * sz) * ws;
            r[2] = (sy) * ws;
            r[3] = (cx * sz + sx * sy * cz) * ws;
            r[4] = (cx * cz - sx * sy * sz) * ws;
            r[5] = (-sx * cy) * ws;
            r[6] = (sx * sz - cx * sy * cz) * ws;
            r[7] = (sx * cz + cx * sy * sz) * ws;
            r[8] = (cx * cy) * ws;
            r[9]  = wgt * tx;
            r[10] = wgt * ty;
            r[11] = wgt * tz;

#pragma unroll
            for (int k = 0; k < 12; ++k) racc[k] += r[k];
#pragma unroll
            for (int i = 0; i < 3; ++i) {
#pragma unroll
                for (int j = 0; j < 3; ++j) {
                    const int s = pi * 3 + j;       // short index 0..23 (static)
                    aw[i * 12 + (s >> 1)] |= ((unsigned)f2bf(r[i * 3 + j])) << (16 * (s & 1));
                }
            }
        }

        // write 3 real rows + 1 zero pad row, 48B each at col pg*24
        unsigned short* arow = Ash + (bsl * 4) * LDP + pg * 24;
#pragma unroll
        for (int i = 0; i < 3; ++i) {
            unsigned short* d = arow + i * LDP;
            u32x4 w0 = { aw[i*12+0], aw[i*12+1], aw[i*12+2],  aw[i*12+3]  };
            u32x4 w1 = { aw[i*12+4], aw[i*12+5], aw[i*12+6],  aw[i*12+7]  };
            u32x4 w2 = { aw[i*12+8], aw[i*12+9], aw[i*12+10], aw[i*12+11] };
            *reinterpret_cast<u32x4*>(d)      = w0;
            *reinterpret_cast<u32x4*>(d + 8)  = w1;
            *reinterpret_cast<u32x4*>(d + 16) = w2;
        }
        {
            unsigned short* d = arow + 3 * LDP;
            u32x4 z = {0u, 0u, 0u, 0u};
            *reinterpret_cast<u32x4*>(d)      = z;
            *reinterpret_cast<u32x4*>(d + 8)  = z;
            *reinterpret_cast<u32x4*>(d + 16) = z;
        }

        // fp32 reduce over the 8 p-groups (lanes bsl*8+pg are contiguous)
#pragma unroll
        for (int m = 1; m < 8; m <<= 1) {
#pragma unroll
            for (int k = 0; k < 12; ++k) racc[k] += __shfl_xor(racc[k], m);
        }
        if (pg == 0) {
#pragma unroll
            for (int k = 0; k < 12; ++k) auxsh[bsl * 12 + k] = racc[k];
        }
    }

    __syncthreads();

    // ---------------- phase 2: 2x2-tile MFMA GEMM from LDS ----------------
    const int w    = t >> 6;
    const int lane = t & 63;
    const int q    = lane >> 4;
    const int r16  = lane & 15;

    const unsigned short* ap0 = Ash + (w * 32 + r16) * LDP + q * 8;
    const unsigned short* ap1 = ap0 + 16 * LDP;
    const unsigned short* bp0 = Bsh + r16 * LDP + q * 8;
    const unsigned short* bp1 = bp0 + 16 * LDP;

    f32x4 acc00 = {0,0,0,0}, acc01 = {0,0,0,0};
    f32x4 acc10 = {0,0,0,0}, acc11 = {0,0,0,0};

#pragma unroll
    for (int ks = 0; ks < 6; ++ks) {
        bf16x8 a0 = *reinterpret_cast<const bf16x8*>(ap0 + ks * 32);
        bf16x8 a1 = *reinterpret_cast<const bf16x8*>(ap1 + ks * 32);
        bf16x8 b0 = *reinterpret_cast<const bf16x8*>(bp0 + ks * 32);
        bf16x8 b1 = *reinterpret_cast<const bf16x8*>(bp1 + ks * 32);
        acc00 = __builtin_amdgcn_mfma_f32_16x16x32_bf16(a0, b0, acc00, 0, 0, 0);
        acc01 = __builtin_amdgcn_mfma_f32_16x16x32_bf16(a0, b1, acc01, 0, 0, 0);
        acc10 = __builtin_amdgcn_mfma_f32_16x16x32_bf16(a1, b0, acc10, 0, 0, 0);
        acc11 = __builtin_amdgcn_mfma_f32_16x16x32_bf16(a1, b1, acc11, 0, 0, 0);
    }

    // fp32 epilogue, direct acc-layout stores.
    const int v0 = bx * 32 + r16;
    const int v1 = v0 + 16;
    float b0x = 0, b0y = 0, b0z = 0, b1x = 0, b1y = 0, b1z = 0;
    if (v0 < NV) { const float* b = bverts + (size_t)v0 * 3; b0x = b[0]; b0y = b[1]; b0z = b[2]; }
    if (v1 < NV) { const float* b = bverts + (size_t)v1 * 3; b1x = b[0]; b1y = b[1]; b1z = b[2]; }

#pragma unroll
    for (int mi = 0; mi < 2; ++mi) {
        const int bsl = (2 * w + mi) * 4 + q;
        const int bs  = by * 32 + bsl;
        const float4 R0 = *reinterpret_cast<const float4*>(auxsh + bsl * 12);
        const float4 R1 = *reinterpret_cast<const float4*>(auxsh + bsl * 12 + 4);
        const float4 R2 = *reinterpret_cast<const float4*>(auxsh + bsl * 12 + 8);
        const f32x4 a0 = mi ? acc10 : acc00;
        const f32x4 a1 = mi ? acc11 : acc01;

        if (v0 < NV) {
            float* po = out + ((size_t)bs * NV + v0) * 3;
            po[0] = a0[0] + R0.x * b0x + R0.y * b0y + R0.z * b0z + R2.y;
            po[1] = a0[1] + R0.w * b0x + R1.x * b0y + R1.y * b0z + R2.z;
            po[2] = a0[2] + R1.z * b0x + R1.w * b0y + R2.x * b0z + R2.w;
        }
        if (v1 < NV) {
            float* po = out + ((size_t)bs * NV + v1) * 3;
            po[0] = a1[0] + R0.x * b1x + R0.y * b1y + R0.z * b1z + R2.y;
            po[1] = a1[1] + R0.w * b1x + R1.x * b1y + R1.y * b1z + R2.z;
            po[2] = a1[2] + R1.z * b1x + R1.w * b1y + R2.x * b1z + R2.w;
        }
    }
}

extern "C" void kernel_launch(void* const* d_in, const int* in_sizes, int n_in,
                              void* d_out, int out_size, void* d_ws, size_t ws_size,
                              hipStream_t stream) {
    const float* scales     = (const float*)d_in[0];
    const float* transforms = (const float*)d_in[1];
    const float* weights    = (const float*)d_in[2];
    const float* offsets    = (const float*)d_in[3];
    const float* bverts     = (const float*)d_in[4];
    float* out = (float*)d_out;

    // Workspace intentionally unused: single fused launch, all staging in LDS.
    (void)d_ws; (void)ws_size;

    fused_kernel<<<dim3(GXN, GYM), dim3(256), 0, stream>>>(
        scales, transforms, weights, offsets, bverts, out);
}